// Round 1
// baseline (6828.185 us; speedup 1.0000x reference)
//
#include <hip/hip_runtime.h>
#include <stdint.h>

typedef unsigned short u16;
typedef unsigned int   u32;

typedef short bf16x8 __attribute__((ext_vector_type(8)));   // 8 bf16 in 4 VGPRs
typedef float f32x4  __attribute__((ext_vector_type(4)));

#define NROWS  2048
#define HID    256
#define BATCH  8
#define NSTEPS 10
#define MTILE  16            // rows per workgroup
#define NWGS   (NROWS/MTILE) // 128
#define THREADS 512          // 8 waves

// ---------- helpers ----------
__device__ __forceinline__ u16 f2bf(float f) {
    union { float f; u32 u; } v; v.f = f;
    u32 r = (v.u + 0x7FFFu + ((v.u >> 16) & 1u)) >> 16;   // RNE
    return (u16)r;
}
__device__ __forceinline__ float sigm(float x) {
    return 1.0f / (1.0f + __expf(-x));
}
__device__ __forceinline__ float ftanh(float x) {
    x = fminf(fmaxf(x, -15.0f), 15.0f);
    float a = __expf(2.0f * x);
    return (a - 1.0f) / (a + 1.0f);
}
__device__ __forceinline__ f32x4 mfma16(bf16x8 a, bf16x8 b, f32x4 c) {
    return __builtin_amdgcn_mfma_f32_16x16x32_bf16(a, b, c, 0, 0, 0);
}
// packed weight B-fragment load: contiguous 16B per lane, 1KB per wave-load
__device__ __forceinline__ bf16x8 loadB(const u16* __restrict__ base, int ct, int kt, int ln) {
    return ((const bf16x8*)base)[(ct * 8 + kt) * 64 + ln];
}
// A-fragment from swizzled LDS tile [16][256] bf16: lane holds row=ln&15, k=kt*32+8*(ln>>4)+j
__device__ __forceinline__ bf16x8 ldsA(const u16* X, int kt, int lr, int lg) {
    int byte = lr * 512 + kt * 64 + lg * 16;
    byte ^= (lr & 7) << 4;                 // XOR swizzle (T2 / G4)
    return *(const bf16x8*)((const char*)X + byte);
}
__device__ __forceinline__ void st16(u16* X, int row, int col, u16 v) {
    int byte = row * 512 + col * 2;
    byte ^= (row & 7) << 4;
    *(u16*)((char*)X + byte) = v;
}

// ---------- setup kernels ----------
// Wz[a][b] = sum_c Wf2[a][c] * Ws2[c][b],  Wf2 = Wf_w[:,256:512]
__global__ __launch_bounds__(256) void stode_wz(const float* __restrict__ Wf,
                                                const float* __restrict__ Ws2,
                                                float* __restrict__ Wz) {
    int a = blockIdx.x;        // 0..255
    int b = threadIdx.x;       // 0..255
    const float* wf2 = Wf + a * 512 + 256;
    float acc = 0.0f;
    for (int c = 0; c < 256; ++c) acc += wf2[c] * Ws2[c * 256 + b];
    Wz[a * 256 + b] = acc;
}
// biasf[a] = Wf_b[a] + sum_c Wf2[a][c]*Ws2_b[c]
__global__ __launch_bounds__(256) void stode_biasf(const float* __restrict__ Wf,
                                                   const float* __restrict__ Ws2b,
                                                   const float* __restrict__ Wfb,
                                                   float* __restrict__ biasf) {
    int a = threadIdx.x;
    const float* wf2 = Wf + a * 512 + 256;
    float acc = Wfb[a];
    for (int c = 0; c < 256; ++c) acc += wf2[c] * Ws2b[c];
    biasf[a] = acc;
}
// pack weights into MFMA-B streaming order, bf16
// P1: 48 ct (ct<32 -> Wg cols, else Ws1), P2: 32 ct (ct<16 -> Wc, else Wz), P3: 16 ct (Wf1)
__global__ __launch_bounds__(256) void stode_pack(const float* __restrict__ Wg,
                                                  const float* __restrict__ Ws1,
                                                  const float* __restrict__ Wc,
                                                  const float* __restrict__ Wz,
                                                  const float* __restrict__ Wf,
                                                  u16* __restrict__ P1,
                                                  u16* __restrict__ P2,
                                                  u16* __restrict__ P3) {
    int i = blockIdx.x * 256 + threadIdx.x;   // 0..393215
    const int NP1 = 48 * 8 * 64 * 8;          // 196608
    const int NP2 = 32 * 8 * 64 * 8;          // 131072
    int region, local;
    if (i < NP1)            { region = 0; local = i; }
    else if (i < NP1 + NP2) { region = 1; local = i - NP1; }
    else                    { region = 2; local = i - NP1 - NP2; }
    int j    = local & 7;
    int lane = (local >> 3) & 63;
    int kt   = (local >> 9) & 7;
    int ct   = local >> 12;
    int k = kt * 32 + (lane >> 4) * 8 + j;
    int c = lane & 15;
    if (region == 0) {
        float v = (ct < 32) ? Wg[(16 * ct + c) * 256 + k]
                            : Ws1[(16 * (ct - 32) + c) * 256 + k];
        P1[local] = f2bf(v);
    } else if (region == 1) {
        float v = (ct < 16) ? Wc[(16 * ct + c) * 256 + k]
                            : Wz[(16 * (ct - 16) + c) * 256 + k];
        P2[local] = f2bf(v);
    } else {
        float v = Wf[(16 * ct + c) * 512 + k];   // Wf1 = Wf_w[:, :256], row stride 512
        P3[local] = f2bf(v);
    }
}

// ---------- main persistent integrator ----------
__global__ __launch_bounds__(THREADS) void stode_main(
    const float* __restrict__ h0, const float* __restrict__ tspans,
    const float* __restrict__ Wg_b, const float* __restrict__ Wc_b,
    const float* __restrict__ Wt,   const float* __restrict__ Ws1_b,
    const u16* __restrict__ P1p, const u16* __restrict__ P2p, const u16* __restrict__ P3p,
    const float* __restrict__ biasf, float* __restrict__ out)
{
    __shared__ u16 X1 [MTILE * HID];   // E (eval input), bf16 swizzled
    __shared__ u16 X2a[MTILE * HID];   // r * E
    __shared__ u16 X2b[MTILE * HID];   // tanh(S1)
    __shared__ u16 X3 [MTILE * HID];   // dh_temp

    const int tid = threadIdx.x;
    const int wv  = tid >> 6;
    const int ln  = tid & 63;
    const int lr  = ln & 15;
    const int lg  = ln >> 4;
    const int wg  = blockIdx.x;

    // per-thread bias / Wt preload (cols = 32*wv + 16*t + lr)
    float bz[2], br[2], bs1[2], bc[2], bfv[2], wtv[2];
    #pragma unroll
    for (int t = 0; t < 2; ++t) {
        int c = 32 * wv + 16 * t + lr;
        bz[t]  = Wg_b[c];
        br[t]  = Wg_b[256 + c];
        bs1[t] = Ws1_b[c];
        bc[t]  = Wc_b[c];
        bfv[t] = biasf[c];
        wtv[t] = Wt[c];
    }

    // state at C/D fragment positions: row = 4*lg + r, col = 32*wv + 16*t + lr
    float y[2][4], k1[2][4], k2[2][4], k3[2][4], k4[2][4], E[2][4], zreg[2][4];
    #pragma unroll
    for (int t = 0; t < 2; ++t)
        #pragma unroll
        for (int r = 0; r < 4; ++r) {
            int row = wg * MTILE + 4 * lg + r;
            int col = 32 * wv + 16 * t + lr;
            y[t][r] = h0[row * 256 + col];
        }

    auto EVAL = [&](float te, float (&kv)[2][4]) {
        // stage X1 = bf16(E)
        #pragma unroll
        for (int t = 0; t < 2; ++t)
            #pragma unroll
            for (int r = 0; r < 4; ++r)
                st16(X1, 4 * lg + r, 32 * wv + 16 * t + lr, f2bf(E[t][r]));
        __syncthreads();   // B1

        // ---- P1: G(z), G(r), S1  (K=256) ----
        bf16x8 af[8];
        #pragma unroll
        for (int kt = 0; kt < 8; ++kt) af[kt] = ldsA(X1, kt, lr, lg);
        f32x4 aZ[2], aR[2], aS[2];
        #pragma unroll
        for (int t = 0; t < 2; ++t) {
            aZ[t] = f32x4{0.f, 0.f, 0.f, 0.f};
            aR[t] = f32x4{0.f, 0.f, 0.f, 0.f};
            aS[t] = f32x4{0.f, 0.f, 0.f, 0.f};
        }
        #pragma unroll
        for (int t = 0; t < 2; ++t) {
            const int ctz = 2 * wv + t, ctr = 16 + 2 * wv + t, cts = 32 + 2 * wv + t;
            #pragma unroll
            for (int kt = 0; kt < 8; ++kt) {
                aZ[t] = mfma16(af[kt], loadB(P1p, ctz, kt, ln), aZ[t]);
                aR[t] = mfma16(af[kt], loadB(P1p, ctr, kt, ln), aR[t]);
                aS[t] = mfma16(af[kt], loadB(P1p, cts, kt, ln), aS[t]);
            }
        }
        // epilogue: z,r in regs (positions match state); write tanh(S1), r*E to LDS
        #pragma unroll
        for (int t = 0; t < 2; ++t)
            #pragma unroll
            for (int r = 0; r < 4; ++r) {
                zreg[t][r] = sigm(aZ[t][r] + bz[t]);
                float rr   = sigm(aR[t][r] + br[t]);
                float s    = ftanh(aS[t][r] + bs1[t]);
                int row = 4 * lg + r, col = 32 * wv + 16 * t + lr;
                st16(X2b, row, col, f2bf(s));
                st16(X2a, row, col, f2bf(rr * E[t][r]));
            }
        __syncthreads();   // B2

        // ---- P2: C = (r*E)@Wc^T,  T1 = tanh(S1)@Wz^T ----
        bf16x8 aa[8], ab[8];
        #pragma unroll
        for (int kt = 0; kt < 8; ++kt) {
            aa[kt] = ldsA(X2a, kt, lr, lg);
            ab[kt] = ldsA(X2b, kt, lr, lg);
        }
        f32x4 aC[2], aT[2];
        #pragma unroll
        for (int t = 0; t < 2; ++t) {
            aC[t] = f32x4{0.f, 0.f, 0.f, 0.f};
            aT[t] = f32x4{0.f, 0.f, 0.f, 0.f};
        }
        #pragma unroll
        for (int t = 0; t < 2; ++t) {
            const int ctc = 2 * wv + t, ctt = 16 + 2 * wv + t;
            #pragma unroll
            for (int kt = 0; kt < 8; ++kt) {
                aC[t] = mfma16(aa[kt], loadB(P2p, ctc, kt, ln), aC[t]);
                aT[t] = mfma16(ab[kt], loadB(P2p, ctt, kt, ln), aT[t]);
            }
        }
        // epilogue: h_tilde, dh_temp -> X3
        float tm0 = ftanh(te * wtv[0]);
        float tm1 = ftanh(te * wtv[1]);
        #pragma unroll
        for (int t = 0; t < 2; ++t)
            #pragma unroll
            for (int r = 0; r < 4; ++r) {
                float ht = ftanh(aC[t][r] + bc[t]) + (t == 0 ? tm0 : tm1);
                float dh = (1.0f - zreg[t][r]) * (ht - E[t][r]);
                st16(X3, 4 * lg + r, 32 * wv + 16 * t + lr, f2bf(dh));
            }
        __syncthreads();   // B3

        // ---- P3: F = tanh(dh_temp@Wf1^T + T1 + biasf) ----
        bf16x8 a3[8];
        #pragma unroll
        for (int kt = 0; kt < 8; ++kt) a3[kt] = ldsA(X3, kt, lr, lg);
        f32x4 aF[2];
        #pragma unroll
        for (int t = 0; t < 2; ++t) aF[t] = f32x4{0.f, 0.f, 0.f, 0.f};
        #pragma unroll
        for (int t = 0; t < 2; ++t) {
            const int ct = 2 * wv + t;
            #pragma unroll
            for (int kt = 0; kt < 8; ++kt)
                aF[t] = mfma16(a3[kt], loadB(P3p, ct, kt, ln), aF[t]);
        }
        #pragma unroll
        for (int t = 0; t < 2; ++t)
            #pragma unroll
            for (int r = 0; r < 4; ++r)
                kv[t][r] = ftanh(aF[t][r] + aT[t][r] + bfv[t]);
    };

    const float third = 1.0f / 3.0f;
    for (int b = 0; b < BATCH; ++b) {
        float t0 = tspans[2 * b], t1 = tspans[2 * b + 1];
        float dt = (t1 - t0) / 10.0f;
        for (int s = 0; s < NSTEPS; ++s) {
            float tb = t0 + (float)s * dt;
            // k1
            #pragma unroll
            for (int t = 0; t < 2; ++t)
                #pragma unroll
                for (int r = 0; r < 4; ++r) E[t][r] = y[t][r];
            EVAL(tb, k1);
            // k2
            #pragma unroll
            for (int t = 0; t < 2; ++t)
                #pragma unroll
                for (int r = 0; r < 4; ++r) E[t][r] = y[t][r] + (dt * third) * k1[t][r];
            EVAL(tb + dt * third, k2);
            // k3
            #pragma unroll
            for (int t = 0; t < 2; ++t)
                #pragma unroll
                for (int r = 0; r < 4; ++r) E[t][r] = y[t][r] + dt * (k2[t][r] - third * k1[t][r]);
            EVAL(tb + dt * 2.0f * third, k3);
            // k4
            #pragma unroll
            for (int t = 0; t < 2; ++t)
                #pragma unroll
                for (int r = 0; r < 4; ++r) E[t][r] = y[t][r] + dt * ((k1[t][r] - k2[t][r]) + k3[t][r]);
            EVAL(tb + dt, k4);
            // y update (3/8 rule)
            #pragma unroll
            for (int t = 0; t < 2; ++t)
                #pragma unroll
                for (int r = 0; r < 4; ++r)
                    y[t][r] += dt * 0.125f * ((k1[t][r] + 3.0f * (k2[t][r] + k3[t][r])) + k4[t][r]);
        }
        // interval output
        #pragma unroll
        for (int t = 0; t < 2; ++t)
            #pragma unroll
            for (int r = 0; r < 4; ++r) {
                int row = wg * MTILE + 4 * lg + r;
                int col = 32 * wv + 16 * t + lr;
                out[(b * NROWS + row) * 256 + col] = y[t][r];
            }
    }
}

extern "C" void kernel_launch(void* const* d_in, const int* in_sizes, int n_in,
                              void* d_out, int out_size, void* d_ws, size_t ws_size,
                              hipStream_t stream) {
    (void)in_sizes; (void)n_in; (void)out_size; (void)ws_size;
    const float* h0    = (const float*)d_in[0];
    const float* ts    = (const float*)d_in[1];
    // d_in[2] = adj_matrices : unused (spectral_reg is None)
    const float* Wg_w  = (const float*)d_in[3];
    const float* Wg_b  = (const float*)d_in[4];
    const float* Wc_w  = (const float*)d_in[5];
    const float* Wc_b  = (const float*)d_in[6];
    const float* Wt_w  = (const float*)d_in[7];
    const float* Ws1_w = (const float*)d_in[8];
    const float* Ws1_b = (const float*)d_in[9];
    const float* Ws2_w = (const float*)d_in[10];
    const float* Ws2_b = (const float*)d_in[11];
    const float* Wf_w  = (const float*)d_in[12];
    const float* Wf_b  = (const float*)d_in[13];

    char* ws = (char*)d_ws;
    u16*   P1    = (u16*)(ws);              // 393216 B
    u16*   P2    = (u16*)(ws + 393216);     // 262144 B
    u16*   P3    = (u16*)(ws + 655360);     // 131072 B
    float* Wz    = (float*)(ws + 786432);   // 262144 B
    float* biasf = (float*)(ws + 1048576);  //   1024 B

    hipLaunchKernelGGL(stode_wz,    dim3(256),  dim3(256), 0, stream, Wf_w, Ws2_w, Wz);
    hipLaunchKernelGGL(stode_biasf, dim3(1),    dim3(256), 0, stream, Wf_w, Ws2_b, Wf_b, biasf);
    hipLaunchKernelGGL(stode_pack,  dim3(1536), dim3(256), 0, stream, Wg_w, Ws1_w, Wc_w, Wz, Wf_w, P1, P2, P3);
    hipLaunchKernelGGL(stode_main,  dim3(NWGS), dim3(THREADS), 0, stream,
                       h0, ts, Wg_b, Wc_b, Wt_w, Ws1_b, P1, P2, P3, biasf, (float*)d_out);
}

// Round 2
// 5398.109 us; speedup vs baseline: 1.2649x; 1.2649x over previous
//
#include <hip/hip_runtime.h>
#include <stdint.h>

typedef unsigned short u16;
typedef unsigned int   u32;

typedef short bf16x8 __attribute__((ext_vector_type(8)));   // 8 bf16 in 4 VGPRs
typedef float f32x4  __attribute__((ext_vector_type(4)));

#define NROWS  2048
#define HID    256
#define BATCH  8
#define NSTEPS 10
#define MTILE  16            // rows per workgroup
#define NWGS   (NROWS/MTILE) // 128
#define THREADS 512          // 8 waves

// ---------- helpers ----------
__device__ __forceinline__ u16 f2bf(float f) {
    union { float f; u32 u; } v; v.f = f;
    u32 r = (v.u + 0x7FFFu + ((v.u >> 16) & 1u)) >> 16;   // RNE
    return (u16)r;
}
__device__ __forceinline__ float sigm(float x) {
    return 1.0f / (1.0f + __expf(-x));
}
__device__ __forceinline__ float ftanh(float x) {
    x = fminf(fmaxf(x, -15.0f), 15.0f);
    float a = __expf(2.0f * x);
    return (a - 1.0f) / (a + 1.0f);
}
__device__ __forceinline__ f32x4 mfma16(bf16x8 a, bf16x8 b, f32x4 c) {
    return __builtin_amdgcn_mfma_f32_16x16x32_bf16(a, b, c, 0, 0, 0);
}
// packed weight B-fragment load: contiguous 16B per lane, 1KB per wave-load
__device__ __forceinline__ bf16x8 loadB(const u16* __restrict__ base, int ct, int kt, int ln) {
    return ((const bf16x8*)base)[(ct * 8 + kt) * 64 + ln];
}
// barrier that does NOT drain vmcnt: LDS visibility via lgkmcnt(0) only.
// Streamed global loads stay in flight across it (T3/T4).
__device__ __forceinline__ void barrier_lgkm() {
    asm volatile("s_waitcnt lgkmcnt(0)" ::: "memory");
    __builtin_amdgcn_s_barrier();
    asm volatile("" ::: "memory");
}

// ---------- setup kernels (unchanged) ----------
__global__ __launch_bounds__(256) void stode_wz(const float* __restrict__ Wf,
                                                const float* __restrict__ Ws2,
                                                float* __restrict__ Wz) {
    int a = blockIdx.x;
    int b = threadIdx.x;
    const float* wf2 = Wf + a * 512 + 256;
    float acc = 0.0f;
    for (int c = 0; c < 256; ++c) acc += wf2[c] * Ws2[c * 256 + b];
    Wz[a * 256 + b] = acc;
}
__global__ __launch_bounds__(256) void stode_biasf(const float* __restrict__ Wf,
                                                   const float* __restrict__ Ws2b,
                                                   const float* __restrict__ Wfb,
                                                   float* __restrict__ biasf) {
    int a = threadIdx.x;
    const float* wf2 = Wf + a * 512 + 256;
    float acc = Wfb[a];
    for (int c = 0; c < 256; ++c) acc += wf2[c] * Ws2b[c];
    biasf[a] = acc;
}
__global__ __launch_bounds__(256) void stode_pack(const float* __restrict__ Wg,
                                                  const float* __restrict__ Ws1,
                                                  const float* __restrict__ Wc,
                                                  const float* __restrict__ Wz,
                                                  const float* __restrict__ Wf,
                                                  u16* __restrict__ P1,
                                                  u16* __restrict__ P2,
                                                  u16* __restrict__ P3) {
    int i = blockIdx.x * 256 + threadIdx.x;
    const int NP1 = 48 * 8 * 64 * 8;
    const int NP2 = 32 * 8 * 64 * 8;
    int region, local;
    if (i < NP1)            { region = 0; local = i; }
    else if (i < NP1 + NP2) { region = 1; local = i - NP1; }
    else                    { region = 2; local = i - NP1 - NP2; }
    int j    = local & 7;
    int lane = (local >> 3) & 63;
    int kt   = (local >> 9) & 7;
    int ct   = local >> 12;
    int k = kt * 32 + (lane >> 4) * 8 + j;
    int c = lane & 15;
    if (region == 0) {
        float v = (ct < 32) ? Wg[(16 * ct + c) * 256 + k]
                            : Ws1[(16 * (ct - 32) + c) * 256 + k];
        P1[local] = f2bf(v);
    } else if (region == 1) {
        float v = (ct < 16) ? Wc[(16 * ct + c) * 256 + k]
                            : Wz[(16 * (ct - 16) + c) * 256 + k];
        P2[local] = f2bf(v);
    } else {
        float v = Wf[(16 * ct + c) * 512 + k];
        P3[local] = f2bf(v);
    }
}

// ---------- main persistent integrator ----------
// LDS layout (bytes): X1/X3 alias @0 (8KB), X2a @8192 (8KB), X2b @16384 (8KB),
// WLDS (LDS-resident R-stream) @24576 (128KB). Total 152 KB.
#define X1B   0
#define X2aB  8192
#define X2bB  16384
#define WLB   24576

__global__ __launch_bounds__(THREADS, 2) void stode_main(
    const float* __restrict__ h0, const float* __restrict__ tspans,
    const float* __restrict__ Wg_b, const float* __restrict__ Wc_b,
    const float* __restrict__ Wt,   const float* __restrict__ Ws1_b,
    const u16* __restrict__ P1p, const u16* __restrict__ P2p, const u16* __restrict__ P3p,
    const float* __restrict__ biasf, float* __restrict__ out)
{
    __shared__ u16 SH[77824];   // 155648 bytes
    char* shb = (char*)SH;

    const int tid = threadIdx.x;
    const int wv  = tid >> 6;
    const int ln  = tid & 63;
    const int lr  = ln & 15;
    const int lg  = ln >> 4;
    const int wg  = blockIdx.x;

    // swizzled activation-tile accessors
    auto ldsA = [&](int xb, int kt) -> bf16x8 {
        int byte = xb + lr * 512 + kt * 64 + lg * 16;
        byte ^= (lr & 7) << 4;
        return *(const bf16x8*)(shb + byte);
    };
    auto st16 = [&](int xb, int row, int col, u16 v) {
        int byte = xb + row * 512 + col * 2;
        byte ^= (row & 7) << 4;
        *(u16*)(shb + byte) = v;
    };
    // LDS-resident R fragment (lane-contiguous, no swizzle needed)
    auto ldsR = [&](int t, int kt) -> bf16x8 {
        return *(const bf16x8*)(shb + WLB + (((wv * 16 + t * 8 + kt) << 10) | (ln << 4)));
    };

    // ---- one-time residency fill ----
    // REG-resident Z stream: 16 frags = 64 VGPRs persistent
    bf16x8 zf[2][8];
    #pragma unroll
    for (int t = 0; t < 2; ++t)
        #pragma unroll
        for (int kt = 0; kt < 8; ++kt)
            zf[t][kt] = loadB(P1p, 2 * wv + t, kt, ln);
    // LDS-resident R stream: 16 frags/wave
    #pragma unroll
    for (int t = 0; t < 2; ++t)
        #pragma unroll
        for (int kt = 0; kt < 8; ++kt) {
            bf16x8 f = loadB(P1p, 16 + 2 * wv + t, kt, ln);
            *(bf16x8*)(shb + WLB + (((wv * 16 + t * 8 + kt) << 10) | (ln << 4))) = f;
        }

    // biases / Wt (cols = 32*wv + 16*t + lr)
    float bz[2], br[2], bs1[2], bc[2], bfv[2], wtv[2];
    #pragma unroll
    for (int t = 0; t < 2; ++t) {
        int c = 32 * wv + 16 * t + lr;
        bz[t]  = Wg_b[c];
        br[t]  = Wg_b[256 + c];
        bs1[t] = Ws1_b[c];
        bc[t]  = Wc_b[c];
        bfv[t] = biasf[c];
        wtv[t] = Wt[c];
    }

    // state at C/D fragment positions: row = 4*lg + r, col = 32*wv + 16*t + lr
    float y[2][4], k1[2][4], k2[2][4], k3[2][4], k4[2][4], E[2][4], zreg[2][4];
    #pragma unroll
    for (int t = 0; t < 2; ++t)
        #pragma unroll
        for (int r = 0; r < 4; ++r) {
            int row = wg * MTILE + 4 * lg + r;
            int col = 32 * wv + 16 * t + lr;
            y[t][r] = h0[row * 256 + col];
        }

    __syncthreads();   // residency fill visible (once; full drain OK here)

    auto EVAL = [&](float te, float (&kv)[2][4]) {
        bf16x8 sSa[2][4], sSb[2][4], sCa[2][4], sCb[2][4];
        bf16x8 sTa[2][4], sTb[2][4], sFa[2][4], sFb[2][4];

        // issue S half-1 (consumed mid-P1)
        #pragma unroll
        for (int t = 0; t < 2; ++t)
            #pragma unroll
            for (int kk = 0; kk < 4; ++kk)
                sSa[t][kk] = loadB(P1p, 32 + 2 * wv + t, kk, ln);

        // stage X1 = bf16(E)
        #pragma unroll
        for (int t = 0; t < 2; ++t)
            #pragma unroll
            for (int r = 0; r < 4; ++r)
                st16(X1B, 4 * lg + r, 32 * wv + 16 * t + lr, f2bf(E[t][r]));
        barrier_lgkm();   // B1 (vmem stays in flight)

        // ---- P1: Z (reg), R (lds), S (stream) over kt-halves ----
        f32x4 aZ[2], aR[2], aS[2];
        #pragma unroll
        for (int t = 0; t < 2; ++t) {
            aZ[t] = f32x4{0.f, 0.f, 0.f, 0.f};
            aR[t] = f32x4{0.f, 0.f, 0.f, 0.f};
            aS[t] = f32x4{0.f, 0.f, 0.f, 0.f};
        }
        bf16x8 af[4];
        #pragma unroll
        for (int kk = 0; kk < 4; ++kk) af[kk] = ldsA(X1B, kk);
        #pragma unroll
        for (int t = 0; t < 2; ++t)
            #pragma unroll
            for (int kk = 0; kk < 4; ++kk) aZ[t] = mfma16(af[kk], zf[t][kk], aZ[t]);
        // issue S half-2
        #pragma unroll
        for (int t = 0; t < 2; ++t)
            #pragma unroll
            for (int kk = 0; kk < 4; ++kk)
                sSb[t][kk] = loadB(P1p, 32 + 2 * wv + t, 4 + kk, ln);
        #pragma unroll
        for (int t = 0; t < 2; ++t)
            #pragma unroll
            for (int kk = 0; kk < 4; ++kk) aR[t] = mfma16(af[kk], ldsR(t, kk), aR[t]);
        #pragma unroll
        for (int t = 0; t < 2; ++t)
            #pragma unroll
            for (int kk = 0; kk < 4; ++kk) aS[t] = mfma16(af[kk], sSa[t][kk], aS[t]);
        // issue C half-1 (consumed in P2)
        #pragma unroll
        for (int t = 0; t < 2; ++t)
            #pragma unroll
            for (int kk = 0; kk < 4; ++kk)
                sCa[t][kk] = loadB(P2p, 2 * wv + t, kk, ln);
        // kt half-2
        #pragma unroll
        for (int kk = 0; kk < 4; ++kk) af[kk] = ldsA(X1B, 4 + kk);
        #pragma unroll
        for (int t = 0; t < 2; ++t)
            #pragma unroll
            for (int kk = 0; kk < 4; ++kk) aZ[t] = mfma16(af[kk], zf[t][4 + kk], aZ[t]);
        // issue C half-2
        #pragma unroll
        for (int t = 0; t < 2; ++t)
            #pragma unroll
            for (int kk = 0; kk < 4; ++kk)
                sCb[t][kk] = loadB(P2p, 2 * wv + t, 4 + kk, ln);
        #pragma unroll
        for (int t = 0; t < 2; ++t)
            #pragma unroll
            for (int kk = 0; kk < 4; ++kk) aR[t] = mfma16(af[kk], ldsR(t, 4 + kk), aR[t]);
        #pragma unroll
        for (int t = 0; t < 2; ++t)
            #pragma unroll
            for (int kk = 0; kk < 4; ++kk) aS[t] = mfma16(af[kk], sSb[t][kk], aS[t]);
        // issue T half-1
        #pragma unroll
        for (int t = 0; t < 2; ++t)
            #pragma unroll
            for (int kk = 0; kk < 4; ++kk)
                sTa[t][kk] = loadB(P2p, 16 + 2 * wv + t, kk, ln);

        // epilogue 1: z,r in regs; write r*E and tanh(S1) tiles
        #pragma unroll
        for (int t = 0; t < 2; ++t)
            #pragma unroll
            for (int r = 0; r < 4; ++r) {
                zreg[t][r] = sigm(aZ[t][r] + bz[t]);
                float rr   = sigm(aR[t][r] + br[t]);
                float s    = ftanh(aS[t][r] + bs1[t]);
                int row = 4 * lg + r, col = 32 * wv + 16 * t + lr;
                st16(X2bB, row, col, f2bf(s));
                st16(X2aB, row, col, f2bf(rr * E[t][r]));
            }
        barrier_lgkm();   // B2

        // ---- P2a: C = (r*E)@Wc^T (streamed C frags) ----
        f32x4 aC[2], aT[2];
        #pragma unroll
        for (int t = 0; t < 2; ++t) {
            aC[t] = f32x4{0.f, 0.f, 0.f, 0.f};
            aT[t] = f32x4{0.f, 0.f, 0.f, 0.f};
        }
        bf16x8 aa[4];
        #pragma unroll
        for (int kk = 0; kk < 4; ++kk) aa[kk] = ldsA(X2aB, kk);
        #pragma unroll
        for (int t = 0; t < 2; ++t)
            #pragma unroll
            for (int kk = 0; kk < 4; ++kk) aC[t] = mfma16(aa[kk], sCa[t][kk], aC[t]);
        // issue T half-2
        #pragma unroll
        for (int t = 0; t < 2; ++t)
            #pragma unroll
            for (int kk = 0; kk < 4; ++kk)
                sTb[t][kk] = loadB(P2p, 16 + 2 * wv + t, 4 + kk, ln);
        #pragma unroll
        for (int kk = 0; kk < 4; ++kk) aa[kk] = ldsA(X2aB, 4 + kk);
        #pragma unroll
        for (int t = 0; t < 2; ++t)
            #pragma unroll
            for (int kk = 0; kk < 4; ++kk) aC[t] = mfma16(aa[kk], sCb[t][kk], aC[t]);
        // issue F half-1
        #pragma unroll
        for (int t = 0; t < 2; ++t)
            #pragma unroll
            for (int kk = 0; kk < 4; ++kk)
                sFa[t][kk] = loadB(P3p, 2 * wv + t, kk, ln);

        // ---- P2b: T1 = tanh(S1)@Wz^T ----
        #pragma unroll
        for (int kk = 0; kk < 4; ++kk) aa[kk] = ldsA(X2bB, kk);
        #pragma unroll
        for (int t = 0; t < 2; ++t)
            #pragma unroll
            for (int kk = 0; kk < 4; ++kk) aT[t] = mfma16(aa[kk], sTa[t][kk], aT[t]);
        // issue F half-2
        #pragma unroll
        for (int t = 0; t < 2; ++t)
            #pragma unroll
            for (int kk = 0; kk < 4; ++kk)
                sFb[t][kk] = loadB(P3p, 2 * wv + t, 4 + kk, ln);
        #pragma unroll
        for (int kk = 0; kk < 4; ++kk) aa[kk] = ldsA(X2bB, 4 + kk);
        #pragma unroll
        for (int t = 0; t < 2; ++t)
            #pragma unroll
            for (int kk = 0; kk < 4; ++kk) aT[t] = mfma16(aa[kk], sTb[t][kk], aT[t]);

        // epilogue 2: dh_temp -> X3 (aliases X1)
        float tm0 = ftanh(te * wtv[0]);
        float tm1 = ftanh(te * wtv[1]);
        #pragma unroll
        for (int t = 0; t < 2; ++t)
            #pragma unroll
            for (int r = 0; r < 4; ++r) {
                float ht = ftanh(aC[t][r] + bc[t]) + (t == 0 ? tm0 : tm1);
                float dh = (1.0f - zreg[t][r]) * (ht - E[t][r]);
                st16(X1B, 4 * lg + r, 32 * wv + 16 * t + lr, f2bf(dh));
            }
        barrier_lgkm();   // B3

        // ---- P3: F = tanh(dh_temp@Wf1^T + T1 + biasf) ----
        f32x4 aF[2];
        #pragma unroll
        for (int t = 0; t < 2; ++t) aF[t] = f32x4{0.f, 0.f, 0.f, 0.f};
        #pragma unroll
        for (int kk = 0; kk < 4; ++kk) aa[kk] = ldsA(X1B, kk);
        #pragma unroll
        for (int t = 0; t < 2; ++t)
            #pragma unroll
            for (int kk = 0; kk < 4; ++kk) aF[t] = mfma16(aa[kk], sFa[t][kk], aF[t]);
        #pragma unroll
        for (int kk = 0; kk < 4; ++kk) aa[kk] = ldsA(X1B, 4 + kk);
        #pragma unroll
        for (int t = 0; t < 2; ++t)
            #pragma unroll
            for (int kk = 0; kk < 4; ++kk) aF[t] = mfma16(aa[kk], sFb[t][kk], aF[t]);
        barrier_lgkm();   // B4: all X3(=X1) reads done before next eval stages X1

        #pragma unroll
        for (int t = 0; t < 2; ++t)
            #pragma unroll
            for (int r = 0; r < 4; ++r)
                kv[t][r] = ftanh(aF[t][r] + aT[t][r] + bfv[t]);
    };

    const float third = 1.0f / 3.0f;
    for (int b = 0; b < BATCH; ++b) {
        float t0 = tspans[2 * b], t1 = tspans[2 * b + 1];
        float dt = (t1 - t0) / 10.0f;
        for (int s = 0; s < NSTEPS; ++s) {
            float tb = t0 + (float)s * dt;
            #pragma unroll
            for (int t = 0; t < 2; ++t)
                #pragma unroll
                for (int r = 0; r < 4; ++r) E[t][r] = y[t][r];
            EVAL(tb, k1);
            #pragma unroll
            for (int t = 0; t < 2; ++t)
                #pragma unroll
                for (int r = 0; r < 4; ++r) E[t][r] = y[t][r] + (dt * third) * k1[t][r];
            EVAL(tb + dt * third, k2);
            #pragma unroll
            for (int t = 0; t < 2; ++t)
                #pragma unroll
                for (int r = 0; r < 4; ++r) E[t][r] = y[t][r] + dt * (k2[t][r] - third * k1[t][r]);
            EVAL(tb + dt * 2.0f * third, k3);
            #pragma unroll
            for (int t = 0; t < 2; ++t)
                #pragma unroll
                for (int r = 0; r < 4; ++r) E[t][r] = y[t][r] + dt * ((k1[t][r] - k2[t][r]) + k3[t][r]);
            EVAL(tb + dt, k4);
            #pragma unroll
            for (int t = 0; t < 2; ++t)
                #pragma unroll
                for (int r = 0; r < 4; ++r)
                    y[t][r] += dt * 0.125f * ((k1[t][r] + 3.0f * (k2[t][r] + k3[t][r])) + k4[t][r]);
        }
        #pragma unroll
        for (int t = 0; t < 2; ++t)
            #pragma unroll
            for (int r = 0; r < 4; ++r) {
                int row = wg * MTILE + 4 * lg + r;
                int col = 32 * wv + 16 * t + lr;
                out[(b * NROWS + row) * 256 + col] = y[t][r];
            }
    }
}

extern "C" void kernel_launch(void* const* d_in, const int* in_sizes, int n_in,
                              void* d_out, int out_size, void* d_ws, size_t ws_size,
                              hipStream_t stream) {
    (void)in_sizes; (void)n_in; (void)out_size; (void)ws_size;
    const float* h0    = (const float*)d_in[0];
    const float* ts    = (const float*)d_in[1];
    // d_in[2] = adj_matrices : unused (spectral_reg is None)
    const float* Wg_w  = (const float*)d_in[3];
    const float* Wg_b  = (const float*)d_in[4];
    const float* Wc_w  = (const float*)d_in[5];
    const float* Wc_b  = (const float*)d_in[6];
    const float* Wt_w  = (const float*)d_in[7];
    const float* Ws1_w = (const float*)d_in[8];
    const float* Ws1_b = (const float*)d_in[9];
    const float* Ws2_w = (const float*)d_in[10];
    const float* Ws2_b = (const float*)d_in[11];
    const float* Wf_w  = (const float*)d_in[12];
    const float* Wf_b  = (const float*)d_in[13];

    char* ws = (char*)d_ws;
    u16*   P1    = (u16*)(ws);              // 393216 B
    u16*   P2    = (u16*)(ws + 393216);     // 262144 B
    u16*   P3    = (u16*)(ws + 655360);     // 131072 B
    float* Wz    = (float*)(ws + 786432);   // 262144 B
    float* biasf = (float*)(ws + 1048576);  //   1024 B

    hipLaunchKernelGGL(stode_wz,    dim3(256),  dim3(256), 0, stream, Wf_w, Ws2_w, Wz);
    hipLaunchKernelGGL(stode_biasf, dim3(1),    dim3(256), 0, stream, Wf_w, Ws2_b, Wf_b, biasf);
    hipLaunchKernelGGL(stode_pack,  dim3(1536), dim3(256), 0, stream, Wg_w, Ws1_w, Wc_w, Wz, Wf_w, P1, P2, P3);
    hipLaunchKernelGGL(stode_main,  dim3(NWGS), dim3(THREADS), 0, stream,
                       h0, ts, Wg_b, Wc_b, Wt_w, Ws1_b, P1, P2, P3, biasf, (float*)d_out);
}